// Round 3
// baseline (251.156 us; speedup 1.0000x reference)
//
#include <hip/hip_runtime.h>
#include <math.h>

#define H 512
#define W 512
#define RM 8
#define TSX 32
#define TSY 32
#define PPT 4                 // vertical pixels per thread
#define LW (TSX + 2*RM)       // 48
#define LH (TSY + 2*RM)       // 48
#define PL (LH * LW)          // 2304 floats per plane

#if defined(__has_builtin) && __has_builtin(__builtin_amdgcn_exp2f)
#define EXP2(x) __builtin_amdgcn_exp2f(x)
#else
#define EXP2(x) exp2f(x)
#endif

__global__ __launch_bounds__(256) void bilateral_kernel(
    const float* __restrict__ img, const float* __restrict__ params,
    float* __restrict__ out)
{
    // 3 SoA planes (r,g,b) — q recomputed per row-tap, amortized over 4 centers
    __shared__ float lds[3 * PL];
    float* __restrict__ pr = lds;
    float* __restrict__ pg = lds + PL;
    float* __restrict__ pb = lds + 2 * PL;

    const int n  = blockIdx.z;
    const int x0 = blockIdx.x * TSX;
    const int y0 = blockIdx.y * TSY;

    const float p0 = params[n*3 + 0];
    const float p1 = params[n*3 + 1];
    const float p2 = params[n*3 + 2];
    const int win = ((int)p0) * 14 + 3;     // window = int(p0)*7*2 + 3
    const int r   = (win - 1) >> 1;
    const float sc = fmaf(p1, 99.0f, 1.0f);
    const float ss = fmaf(p2, 99.0f, 1.0f);
    const float LOG2E = 1.4426950408889634f;
    // values kept at 0..1 scale; 255^2 and log2(e) folded into A (A < 0)
    const float A  = -65025.0f * LOG2E / (2.0f * sc * sc);
    const float Bs = -LOG2E / (2.0f * ss * ss);

    // ---- stage tile + halo (edge-clamped) into 3 SoA planes ----
    const float* imgN = img + (size_t)n * (3 * H * W);
    for (int idx = threadIdx.x; idx < PL; idx += 256) {
        int ly = idx / LW;
        int lx = idx - ly * LW;
        int gy = y0 + ly - RM; gy = gy < 0 ? 0 : (gy > H-1 ? H-1 : gy);
        int gx = x0 + lx - RM; gx = gx < 0 ? 0 : (gx > W-1 ? W-1 : gx);
        int g = gy * W + gx;
        pr[idx] = imgN[g];
        pg[idx] = imgN[H*W + g];
        pb[idx] = imgN[2*H*W + g];
    }
    __syncthreads();

    const int tx = threadIdx.x & (TSX - 1);
    const int tq = threadIdx.x >> 5;        // 0..7, base row = tq*4

    // per-center constants
    float cr2[PPT], cg2[PPT], cb2[PPT], K[PPT];
    float accr[PPT], accg[PPT], accb[PPT], accd[PPT];
    #pragma unroll
    for (int k = 0; k < PPT; ++k) {
        int cb_ = (RM + tq*PPT + k) * LW + (RM + tx);
        float cr = pr[cb_], cg = pg[cb_], cb = pb[cb_];
        K[k]   = A * fmaf(cr, cr, fmaf(cg, cg, cb * cb));   // A*(c.c)
        cr2[k] = -2.0f * A * cr;
        cg2[k] = -2.0f * A * cg;
        cb2[k] = -2.0f * A * cb;
        accr[k] = 0.0f; accg[k] = 0.0f; accb[k] = 0.0f; accd[k] = 0.0f;
    }

    // spatial-x bias (wave-uniform -> SGPRs); masked taps -> -inf -> w = 0
    float bx[2*RM + 1];
    #pragma unroll
    for (int i = 0; i <= 2*RM; ++i) {
        int d  = i - RM;
        int ad = d < 0 ? -d : d;
        bx[i] = (ad <= r) ? Bs * (float)(d*d) : -__builtin_inff();
    }

    // rows j = 0..19 cover the union of the 4 centers' windows
    #pragma unroll 1
    for (int j = 0; j < TSX/TSX*0 + (2*RM + PPT); ++j) {   // 20 rows
        // per-(row,center) constant: K + spatial-y bias (masked -> -inf)
        float ckrow[PPT];
        #pragma unroll
        for (int k = 0; k < PPT; ++k) {
            int dy  = j - RM - k;
            int ady = dy < 0 ? -dy : dy;
            ckrow[k] = K[k] + ((ady <= r) ? Bs * (float)(dy*dy)
                                          : -__builtin_inff());
        }
        const int rb = (tq*PPT + j) * LW + tx;
        const float* __restrict__ lr = &pr[rb];
        const float* __restrict__ lg = &pg[rb];
        const float* __restrict__ lb = &pb[rb];

        #pragma unroll
        for (int i = 0; i <= 2*RM; ++i) {
            float sr = lr[i];
            float sg = lg[i];
            float sb = lb[i];
            float q  = A * fmaf(sr, sr, fmaf(sg, sg, sb * sb)); // A*(s.s)
            float qb = q + bx[i];
            #pragma unroll
            for (int k = 0; k < PPT; ++k) {
                float t = fmaf(cr2[k], sr, qb);
                t = fmaf(cg2[k], sg, t);
                t = fmaf(cb2[k], sb, t);
                float w = EXP2(t + ckrow[k]);
                accr[k] = fmaf(w, sr, accr[k]);
                accg[k] = fmaf(w, sg, accg[k]);
                accb[k] = fmaf(w, sb, accb[k]);
                accd[k] += w;
            }
        }
    }

    float* outN = out + (size_t)n * (3 * H * W);
    #pragma unroll
    for (int k = 0; k < PPT; ++k) {
        const float inv = __builtin_amdgcn_rcpf(accd[k]);
        const int o = (y0 + tq*PPT + k) * W + (x0 + tx);
        outN[o]         = accr[k] * inv;
        outN[H*W + o]   = accg[k] * inv;
        outN[2*H*W + o] = accb[k] * inv;
    }
}

extern "C" void kernel_launch(void* const* d_in, const int* in_sizes, int n_in,
                              void* d_out, int out_size, void* d_ws, size_t ws_size,
                              hipStream_t stream) {
    const float* img    = (const float*)d_in[0];
    const float* params = (const float*)d_in[1];
    float* out          = (float*)d_out;
    dim3 grid(W / TSX, H / TSY, 8);
    bilateral_kernel<<<grid, dim3(256), 0, stream>>>(img, params, out);
}

// Round 4
// 247.847 us; speedup vs baseline: 1.0133x; 1.0133x over previous
//
#include <hip/hip_runtime.h>
#include <math.h>

#define H 512
#define W 512
#define RM 8
#define TSX 32
#define TSY 16
#define PPT 2                 // vertical pixels per thread
#define LW (TSX + 2*RM)       // 48
#define LH (TSY + 2*RM)       // 32
#define PL (LH * LW)          // 1536 floats per plane

#if defined(__has_builtin) && __has_builtin(__builtin_amdgcn_exp2f)
#define EXP2(x) __builtin_amdgcn_exp2f(x)
#else
#define EXP2(x) exp2f(x)
#endif

// 18.4 KB LDS -> 8 blocks/CU; launch_bounds(256,8) pins VGPR<=64 so we are
// wave-cap limited (32 waves/CU), not register limited. Grid 4096 blocks =
// exactly 2 residency passes (8 blocks/CU * 256 CU = 2048 slots) -> no tail.
__global__ __launch_bounds__(256, 8) void bilateral_kernel(
    const float* __restrict__ img, const float* __restrict__ params,
    float* __restrict__ out)
{
    __shared__ float lds[3 * PL];
    float* __restrict__ pr = lds;
    float* __restrict__ pg = lds + PL;
    float* __restrict__ pb = lds + 2 * PL;

    const int n  = blockIdx.z;
    const int x0 = blockIdx.x * TSX;
    const int y0 = blockIdx.y * TSY;

    const float p0 = params[n*3 + 0];
    const float p1 = params[n*3 + 1];
    const float p2 = params[n*3 + 2];
    const int win = ((int)p0) * 14 + 3;     // window = int(p0)*7*2 + 3
    const int r   = (win - 1) >> 1;
    const float sc = fmaf(p1, 99.0f, 1.0f);
    const float ss = fmaf(p2, 99.0f, 1.0f);
    const float LOG2E = 1.4426950408889634f;
    // values kept at 0..1 scale; 255^2 and log2(e) folded into A (A < 0)
    const float A  = -65025.0f * LOG2E / (2.0f * sc * sc);
    const float Bs = -LOG2E / (2.0f * ss * ss);

    // ---- stage tile + halo (edge-clamped) into 3 SoA planes ----
    const float* imgN = img + (size_t)n * (3 * H * W);
    for (int idx = threadIdx.x; idx < PL; idx += 256) {
        int ly = idx / LW;
        int lx = idx - ly * LW;
        int gy = y0 + ly - RM; gy = gy < 0 ? 0 : (gy > H-1 ? H-1 : gy);
        int gx = x0 + lx - RM; gx = gx < 0 ? 0 : (gx > W-1 ? W-1 : gx);
        int g = gy * W + gx;
        pr[idx] = imgN[g];
        pg[idx] = imgN[H*W + g];
        pb[idx] = imgN[2*H*W + g];
    }
    __syncthreads();

    const int tx = threadIdx.x & (TSX - 1);
    const int tq = threadIdx.x >> 5;        // 0..7, base row = tq*PPT

    // per-center constants (expanded-distance algebra):
    // A*|s-c|^2 = A*(s.s) - 2A*(s.c) + A*(c.c)
    float cr2[PPT], cg2[PPT], cb2[PPT], K[PPT];
    float accr[PPT], accg[PPT], accb[PPT], accd[PPT];
    #pragma unroll
    for (int k = 0; k < PPT; ++k) {
        int cb_ = (RM + tq*PPT + k) * LW + (RM + tx);
        float cr = pr[cb_], cg = pg[cb_], cb = pb[cb_];
        K[k]   = A * fmaf(cr, cr, fmaf(cg, cg, cb * cb));   // A*(c.c)
        cr2[k] = -2.0f * A * cr;
        cg2[k] = -2.0f * A * cg;
        cb2[k] = -2.0f * A * cb;
        accr[k] = 0.0f; accg[k] = 0.0f; accb[k] = 0.0f; accd[k] = 0.0f;
    }

    // spatial-x bias (block-uniform -> SGPRs); masked taps -> -inf -> w = 0
    float bx[2*RM + 1];
    #pragma unroll
    for (int i = 0; i <= 2*RM; ++i) {
        int d  = i - RM;
        int ad = d < 0 ? -d : d;
        bx[i] = (ad <= r) ? Bs * (float)(d*d) : -__builtin_inff();
    }

    // rows j = 0..17 cover the union of the PPT centers' windows
    #pragma unroll 1
    for (int j = 0; j < 2*RM + PPT; ++j) {
        float ckrow[PPT];
        #pragma unroll
        for (int k = 0; k < PPT; ++k) {
            int dy  = j - RM - k;
            int ady = dy < 0 ? -dy : dy;
            ckrow[k] = K[k] + ((ady <= r) ? Bs * (float)(dy*dy)
                                          : -__builtin_inff());
        }
        const int rb = (tq*PPT + j) * LW + tx;
        const float* __restrict__ lr = &pr[rb];
        const float* __restrict__ lg = &pg[rb];
        const float* __restrict__ lb = &pb[rb];

        #pragma unroll
        for (int i = 0; i <= 2*RM; ++i) {
            float sr = lr[i];
            float sg = lg[i];
            float sb = lb[i];
            float q  = A * fmaf(sr, sr, fmaf(sg, sg, sb * sb)); // A*(s.s)
            float qb = q + bx[i];
            #pragma unroll
            for (int k = 0; k < PPT; ++k) {
                float t = fmaf(cr2[k], sr, qb);
                t = fmaf(cg2[k], sg, t);
                t = fmaf(cb2[k], sb, t);
                float w = EXP2(t + ckrow[k]);
                accr[k] = fmaf(w, sr, accr[k]);
                accg[k] = fmaf(w, sg, accg[k]);
                accb[k] = fmaf(w, sb, accb[k]);
                accd[k] += w;
            }
        }
    }

    float* outN = out + (size_t)n * (3 * H * W);
    #pragma unroll
    for (int k = 0; k < PPT; ++k) {
        const float inv = __builtin_amdgcn_rcpf(accd[k]);
        const int o = (y0 + tq*PPT + k) * W + (x0 + tx);
        outN[o]         = accr[k] * inv;
        outN[H*W + o]   = accg[k] * inv;
        outN[2*H*W + o] = accb[k] * inv;
    }
}

extern "C" void kernel_launch(void* const* d_in, const int* in_sizes, int n_in,
                              void* d_out, int out_size, void* d_ws, size_t ws_size,
                              hipStream_t stream) {
    const float* img    = (const float*)d_in[0];
    const float* params = (const float*)d_in[1];
    float* out          = (float*)d_out;
    dim3 grid(W / TSX, H / TSY, 8);
    bilateral_kernel<<<grid, dim3(256), 0, stream>>>(img, params, out);
}